// Round 5
// baseline (370.484 us; speedup 1.0000x reference)
//
#include <hip/hip_runtime.h>
#include <math.h>

#define EPS_GS 1e-8f
#define RAD2DEG 57.29577951308232f
#define PI_F 3.14159265358979f
#define ROT_PER_BLOCK 512          // 2 per thread
#define F4_PER_INPUT 1152          // 512*9/4 float4 per input per block

__device__ __forceinline__ float clip10(float x) {
    x = x < -10.f ? -10.f : x;
    x = x >  10.f ?  10.f : x;
    return x;
}

__device__ __forceinline__ float fsqrt(float x) { return __builtin_amdgcn_sqrtf(x); }
__device__ __forceinline__ float frcp(float x)  { return __builtin_amdgcn_rcpf(x); }

// Abramowitz-Stegun 4.4.45: max error 6.76e-5 rad
__device__ __forceinline__ float fast_acos(float x) {
    float ax = fabsf(x);
    float p = fmaf(ax, -0.0187293f, 0.0742610f);
    p = fmaf(ax, p, -0.2121144f);
    p = fmaf(ax, p, 1.5707288f);
    float pos = fsqrt(1.f - ax) * p;
    return x >= 0.f ? pos : PI_F - pos;
}

// v: 3x3 row-major (clipped). R: rotation with columns e1,e2,e3 (det-fixed).
__device__ __forceinline__ void gs_rotmat(const float* v, float* R) {
    float c0x = v[0], c0y = v[3], c0z = v[6];
    float c1x = v[1], c1y = v[4], c1z = v[7];
    float c2x = v[2], c2y = v[5], c2z = v[8];

    float s1 = fmaf(c0x, c0x, fmaf(c0y, c0y, c0z*c0z));
    float inv1 = frcp(fsqrt(s1) + EPS_GS);
    float e1x = c0x*inv1, e1y = c0y*inv1, e1z = c0z*inv1;

    float d = fmaf(e1x, c1x, fmaf(e1y, c1y, e1z*c1z));
    float u2x = fmaf(-d, e1x, c1x), u2y = fmaf(-d, e1y, c1y), u2z = fmaf(-d, e1z, c1z);
    float s2 = fmaf(u2x, u2x, fmaf(u2y, u2y, u2z*u2z));
    float inv2 = frcp(fsqrt(s2) + EPS_GS);
    float e2x = u2x*inv2, e2y = u2y*inv2, e2z = u2z*inv2;

    float d1 = fmaf(e1x, c2x, fmaf(e1y, c2y, e1z*c2z));
    float d2 = fmaf(e2x, c2x, fmaf(e2y, c2y, e2z*c2z));
    float u3x = fmaf(-d1, e1x, fmaf(-d2, e2x, c2x));
    float u3y = fmaf(-d1, e1y, fmaf(-d2, e2y, c2y));
    float u3z = fmaf(-d1, e1z, fmaf(-d2, e2z, c2z));
    float s3 = fmaf(u3x, u3x, fmaf(u3y, u3y, u3z*u3z));
    float inv3 = frcp(fsqrt(s3) + EPS_GS);
    float e3x = u3x*inv3, e3y = u3y*inv3, e3z = u3z*inv3;

    float cxx = e2y*e3z - e2z*e3y;
    float cxy = e2z*e3x - e2x*e3z;
    float cxz = e2x*e3y - e2y*e3x;
    float det = fmaf(e1x, cxx, fmaf(e1y, cxy, e1z*cxz));
    if (det < 0.f) { e3x = -e3x; e3y = -e3y; e3z = -e3z; }

    R[0] = e1x; R[1] = e2x; R[2] = e3x;
    R[3] = e1y; R[4] = e2y; R[5] = e3y;
    R[6] = e1z; R[7] = e2z; R[8] = e3z;
}

__device__ __forceinline__ void accum_rot(const float* pr, const float* tg,
                                          float& lt, float& lf) {
    float pc[9], tc[9];
    #pragma unroll
    for (int m = 0; m < 9; ++m) { pc[m] = clip10(pr[m]); tc[m] = clip10(tg[m]); }

    float Rp[9], Rt[9];
    gs_rotmat(pc, Rp);
    gs_rotmat(tc, Rt);

    float chord = 0.f, tr = 0.f;
    #pragma unroll
    for (int m = 0; m < 9; ++m) {
        float d = Rp[m] - Rt[m];
        chord = fmaf(d, d, chord);
        tr    = fmaf(Rp[m], Rt[m], tr);
    }

    const float trLo = -3.0f + 1e-6f, trHi = 3.0f - 1e-6f;
    tr = tr < trLo ? trLo : (tr > trHi ? trHi : tr);
    float ca = (tr - 1.f) * 0.5f;
    const float cLo = -1.0f + 1e-7f, cHi = 1.0f - 1e-7f;
    ca = ca < cLo ? cLo : (ca > cHi ? cHi : ca);
    float ang = fast_acos(ca) * RAD2DEG;
    if (ang != ang) ang = 180.f;

    float o = 0.f;
    #pragma unroll
    for (int i = 0; i < 3; ++i) {
        #pragma unroll
        for (int j = 0; j < 3; ++j) {
            float s = fmaf(pc[i], pc[j], fmaf(pc[3+i], pc[3+j], pc[6+i]*pc[6+j]));
            s -= (i == j) ? 1.f : 0.f;
            o = fmaf(s, s, o);
        }
    }

    float l2 = 0.f, fb = 0.f;
    #pragma unroll
    for (int m = 0; m < 9; ++m) {
        l2 = fmaf(pc[m], pc[m], l2);
        float d = pc[m] - tg[m];   // fallback uses UNclipped target
        fb = fmaf(d, d, fb);
    }

    lt += fmaf(0.1f, ang, chord) + fmaf(0.01f, o, (1e-4f/9.f)*l2);
    lf += fb;
}

__device__ __forceinline__ float2 block_reduce(float lt, float lf) {
    #pragma unroll
    for (int off = 32; off > 0; off >>= 1) {
        lt += __shfl_down(lt, off, 64);
        lf += __shfl_down(lf, off, 64);
    }
    __shared__ float st[4], sf[4];
    const int lane = threadIdx.x & 63;
    const int wid  = threadIdx.x >> 6;
    if (lane == 0) { st[wid] = lt; sf[wid] = lf; }
    __syncthreads();
    float2 r = make_float2(0.f, 0.f);
    if (threadIdx.x == 0) {
        int nw = (blockDim.x + 63) >> 6;
        for (int w = 0; w < nw; ++w) { r.x += st[w]; r.y += sf[w]; }
    }
    return r;
}

__global__ __launch_bounds__(256)
void rot_loss_kernel(const float* __restrict__ pred, const float* __restrict__ targ,
                     float2* __restrict__ partial) {
    __shared__ float sP[ROT_PER_BLOCK * 9];   // 18432 B
    __shared__ float sT[ROT_PER_BLOCK * 9];   // 18432 B

    const int tid = threadIdx.x;
    const size_t base4 = (size_t)blockIdx.x * F4_PER_INPUT;
    const float4* p4 = reinterpret_cast<const float4*>(pred) + base4;
    const float4* t4 = reinterpret_cast<const float4*>(targ) + base4;
    float4* sP4 = reinterpret_cast<float4*>(sP);
    float4* sT4 = reinterpret_cast<float4*>(sT);

    // Fully-coalesced staging: adjacent lanes -> adjacent 16B. Load all to regs
    // first (10 outstanding dwordx4/thread), then write LDS linearly.
    float4 rp[5], rt[5];
    #pragma unroll
    for (int j = 0; j < 5; ++j) {
        int idx = tid + 256 * j;
        if (idx < F4_PER_INPUT) rp[j] = p4[idx];
    }
    #pragma unroll
    for (int j = 0; j < 5; ++j) {
        int idx = tid + 256 * j;
        if (idx < F4_PER_INPUT) rt[j] = t4[idx];
    }
    #pragma unroll
    for (int j = 0; j < 5; ++j) {
        int idx = tid + 256 * j;
        if (idx < F4_PER_INPUT) { sP4[idx] = rp[j]; sT4[idx] = rt[j]; }
    }
    __syncthreads();

    float lt = 0.f, lf = 0.f;
    // stride-9-float LDS reads: gcd(9,32)=1 -> all banks cycled, conflict-free
    accum_rot(&sP[tid * 9],         &sT[tid * 9],         lt, lf);
    accum_rot(&sP[(tid + 256) * 9], &sT[(tid + 256) * 9], lt, lf);

    float2 r = block_reduce(lt, lf);
    if (threadIdx.x == 0) partial[blockIdx.x] = r;   // unique slot, no atomics
}

__global__ __launch_bounds__(256)
void rot_loss_tail(const float* __restrict__ pred, const float* __restrict__ targ,
                   float2* __restrict__ partial, int pslot, int start, int B) {
    int r = start + blockIdx.x * blockDim.x + threadIdx.x;
    float lt = 0.f, lf = 0.f;
    if (r < B) {
        float a[9], b[9];
        for (int m = 0; m < 9; ++m) { a[m] = pred[(size_t)r*9 + m]; b[m] = targ[(size_t)r*9 + m]; }
        accum_rot(a, b, lt, lf);
    }
    float2 rr = block_reduce(lt, lf);
    if (threadIdx.x == 0) partial[pslot + blockIdx.x] = rr;
}

__global__ __launch_bounds__(1024)
void finalize_kernel(const float2* __restrict__ partial, int nparts,
                     float* __restrict__ out, int B) {
    double t = 0.0, f = 0.0;
    for (int i = threadIdx.x; i < nparts; i += 1024) {
        float2 p = partial[i];
        t += (double)p.x;
        f += (double)p.y;
    }
    #pragma unroll
    for (int off = 32; off > 0; off >>= 1) {
        t += __shfl_down(t, off, 64);
        f += __shfl_down(f, off, 64);
    }
    __shared__ double st[16], sf[16];
    const int lane = threadIdx.x & 63;
    const int wid  = threadIdx.x >> 6;
    if (lane == 0) { st[wid] = t; sf[wid] = f; }
    __syncthreads();
    if (threadIdx.x == 0) {
        double tt = 0.0, ff = 0.0;
        for (int w = 0; w < 16; ++w) { tt += st[w]; ff += sf[w]; }
        double total = tt / (double)B;
        double fb    = ff / (9.0 * (double)B);
        out[0] = isnan(total) ? (float)fb : (float)total;
    }
}

extern "C" void kernel_launch(void* const* d_in, const int* in_sizes, int n_in,
                              void* d_out, int out_size, void* d_ws, size_t ws_size,
                              hipStream_t stream) {
    const float* pred = (const float*)d_in[0];
    const float* targ = (const float*)d_in[1];
    const int n = in_sizes[0];
    const int B = n / 9;

    float2* partial = (float2*)d_ws;

    const int fullBlocks = B / ROT_PER_BLOCK;              // 8192 for B=4.19M
    const int rem        = B - fullBlocks * ROT_PER_BLOCK;
    const int tailBlocks = (rem + 255) / 256;
    if (fullBlocks > 0)
        rot_loss_kernel<<<fullBlocks, 256, 0, stream>>>(pred, targ, partial);
    if (rem > 0)
        rot_loss_tail<<<tailBlocks, 256, 0, stream>>>(
            pred, targ, partial, fullBlocks, fullBlocks * ROT_PER_BLOCK, B);
    finalize_kernel<<<1, 1024, 0, stream>>>(partial, fullBlocks + tailBlocks,
                                            (float*)d_out, B);
}